// Round 1
// baseline (961.976 us; speedup 1.0000x reference)
//
#include <hip/hip_runtime.h>
#include <hip/hip_bf16.h>
#include <math.h>

#define NV 400000
#define GRID_CONV 1563   // ceil(NV/256)

typedef __bf16 bfv8 __attribute__((ext_vector_type(8)));
typedef float f32x4 __attribute__((ext_vector_type(4)));

// ---------------------------------------------------------------------------
// prep: feats (f32) -> fpad (bf16, N+1 rows, row N = 0); zero xpad row N too
// ---------------------------------------------------------------------------
__global__ void prep_feats_k(const float* __restrict__ feats,
                             __bf16* __restrict__ fpad,
                             __bf16* __restrict__ xpad)
{
    long t = (long)blockIdx.x * blockDim.x + threadIdx.x;
    long base = t * 4;
    const long nfeat = (long)NV * 64;
    const long total = (long)(NV + 1) * 64;
    if (base < total) {
        float x0 = 0.f, x1 = 0.f, x2 = 0.f, x3 = 0.f;
        if (base < nfeat) {
            const float4 v = *(const float4*)(feats + base);
            x0 = v.x; x1 = v.y; x2 = v.z; x3 = v.w;
        }
        union { __bf16 b[4]; ushort4 u; } pk;
        pk.b[0] = (__bf16)x0; pk.b[1] = (__bf16)x1;
        pk.b[2] = (__bf16)x2; pk.b[3] = (__bf16)x3;
        *(ushort4*)(fpad + base) = pk.u;
    }
    if (t < 64) xpad[(long)NV * 64 + t] = (__bf16)0.f;
}

// ---------------------------------------------------------------------------
// prep: pack weights into MFMA B-fragment layout.
// wpk[s][k][kc][cb][lane][i] = W_s[k][cin][cout], cin = kc*32+(lane>>4)*8+i,
// cout = cb*16+(lane&15).  s=0: W_init, s=1..3: W_br[d].
// total elements = 4*27*4096 = 442368
// ---------------------------------------------------------------------------
__global__ void prep_w_k(const float* __restrict__ Winit,
                         const float* __restrict__ Wbr,
                         __bf16* __restrict__ wpk)
{
    int e = blockIdx.x * 256 + threadIdx.x;
    int i  = e & 7;
    int l  = (e >> 3) & 63;
    int cb = (e >> 9) & 3;
    int kc = (e >> 11) & 1;
    int kk = e >> 12;          // s*27 + k
    int k  = kk % 27;
    int s  = kk / 27;
    int cin  = kc * 32 + (l >> 4) * 8 + i;
    int cout = cb * 16 + (l & 15);
    float v = (s == 0) ? Winit[(k * 64 + cin) * 64 + cout]
                       : Wbr[(((s - 1) * 27 + k) * 64 + cin) * 64 + cout];
    wpk[e] = (__bf16)v;
}

// ---------------------------------------------------------------------------
// prep: fold BN (+ conv bias) into scale/shift:  y = conv*sc + sh
// sc = g/sqrt(v+eps);  sh = (b - m)*sc + be.   4 sets x 64 ch.
// ---------------------------------------------------------------------------
__global__ void prep_bn_k(const float* __restrict__ b_init, const float* __restrict__ g_init,
                          const float* __restrict__ be_init, const float* __restrict__ m_init,
                          const float* __restrict__ v_init,
                          const float* __restrict__ b_br, const float* __restrict__ g_br,
                          const float* __restrict__ be_br, const float* __restrict__ m_br,
                          const float* __restrict__ v_br,
                          float* __restrict__ scale, float* __restrict__ shiftb)
{
    int t = threadIdx.x;          // 0..255
    int s = t >> 6, c = t & 63;
    float g, be, m, v, b;
    if (s == 0) { g = g_init[c]; be = be_init[c]; m = m_init[c]; v = v_init[c]; b = b_init[c]; }
    else { int o = (s - 1) * 64 + c; g = g_br[o]; be = be_br[o]; m = m_br[o]; v = v_br[o]; b = b_br[o]; }
    float sc = g / sqrtf(v + 1e-5f);
    scale[t]  = sc;
    shiftb[t] = (b - m) * sc + be;
}

// ---------------------------------------------------------------------------
// one 27-tap sub-step: gather A rows (16 rows per rg, 4 rgs = 64 rows/wave),
// load packed B frags, 32 MFMAs. acc layout: acc[rg][cb] = 16x16 D tile.
// ---------------------------------------------------------------------------
__device__ __forceinline__ void conv_tap_accum(const __bf16* __restrict__ src,
                                               const int* __restrict__ nk,
                                               const __bf16* __restrict__ wtap,
                                               long base, int l15, int lg, int lane,
                                               f32x4 acc[4][4])
{
    int idx[4];
#pragma unroll
    for (int rg = 0; rg < 4; rg++) {
        long r = base + rg * 16 + l15;
        r = (r < NV) ? r : (NV - 1);
        idx[rg] = nk[r];
    }
    bfv8 bmat[2][4];
    const bfv8* wp = (const bfv8*)wtap;
#pragma unroll
    for (int kc = 0; kc < 2; kc++)
#pragma unroll
        for (int cb = 0; cb < 4; cb++)
            bmat[kc][cb] = wp[(kc * 4 + cb) * 64 + lane];
#pragma unroll
    for (int rg = 0; rg < 4; rg++) {
        const bfv8* ar = (const bfv8*)(src + (size_t)idx[rg] * 64);
        bfv8 a0 = ar[lg];       // k = 0..31, lane holds k in [lg*8, lg*8+8)
        bfv8 a1 = ar[4 + lg];   // k = 32..63
#pragma unroll
        for (int cb = 0; cb < 4; cb++) {
            acc[rg][cb] = __builtin_amdgcn_mfma_f32_16x16x32_bf16(a0, bmat[0][cb], acc[rg][cb], 0, 0, 0);
            acc[rg][cb] = __builtin_amdgcn_mfma_f32_16x16x32_bf16(a1, bmat[1][cb], acc[rg][cb], 0, 0, 0);
        }
    }
}

// ---------------------------------------------------------------------------
// conv_init: x_init = bnrelu(conv(fpad, nbr[0], W_init)) -> xpad (bf16)
//            + logitpart[row] = x_init[row] . W_out
// ---------------------------------------------------------------------------
__global__ __launch_bounds__(256, 2)
void conv_init_k(const __bf16* __restrict__ fpad, const int* __restrict__ nbr,
                 const __bf16* __restrict__ wpk, const float* __restrict__ scale,
                 const float* __restrict__ shiftb, const float* __restrict__ wout,
                 __bf16* __restrict__ xpad, float* __restrict__ logitpart)
{
    __shared__ __bf16 tile[256 * 64];
    const int tid = threadIdx.x;
    const int wid = tid >> 6, lane = tid & 63;
    const int l15 = lane & 15, lg = lane >> 4;
    const long base = (long)blockIdx.x * 256 + wid * 64;

    f32x4 acc[4][4];
    f32x4 z = {0.f, 0.f, 0.f, 0.f};
#pragma unroll
    for (int a = 0; a < 4; a++)
#pragma unroll
        for (int b = 0; b < 4; b++) acc[a][b] = z;

    for (int k = 0; k < 27; k++)
        conv_tap_accum(fpad, nbr + (size_t)k * NV, wpk + (size_t)k * 4096,
                       base, l15, lg, lane, acc);

    float sc[4], sh[4], wo[4];
#pragma unroll
    for (int cb = 0; cb < 4; cb++) {
        int col = cb * 16 + l15;
        sc[cb] = scale[col]; sh[cb] = shiftb[col]; wo[cb] = wout[col];
    }
    float lacc[4][4];
#pragma unroll
    for (int rg = 0; rg < 4; rg++)
#pragma unroll
        for (int j = 0; j < 4; j++) lacc[rg][j] = 0.f;

#pragma unroll
    for (int rg = 0; rg < 4; rg++)
#pragma unroll
        for (int cb = 0; cb < 4; cb++)
#pragma unroll
            for (int j = 0; j < 4; j++) {
                float y = fmaxf(acc[rg][cb][j] * sc[cb] + sh[cb], 0.f);
                lacc[rg][j] += y * wo[cb];
                tile[(wid * 64 + rg * 16 + lg * 4 + j) * 64 + cb * 16 + l15] = (__bf16)y;
            }
    __syncthreads();

    // coalesced bf16 write of x_init rows
    long grow = (long)blockIdx.x * 256 + tid;
    if (grow < NV) {
        const f32x4* srcp = (const f32x4*)(tile + tid * 64);
        f32x4* dst = (f32x4*)(xpad + grow * 64);
#pragma unroll
        for (int q = 0; q < 8; q++) dst[q] = srcp[q];
    }

    // reduce logit partial over the 16 lanes of each row group
#pragma unroll
    for (int rg = 0; rg < 4; rg++) {
        float red[4];
#pragma unroll
        for (int j = 0; j < 4; j++) {
            float t = lacc[rg][j];
            t += __shfl_xor(t, 1, 64);
            t += __shfl_xor(t, 2, 64);
            t += __shfl_xor(t, 4, 64);
            t += __shfl_xor(t, 8, 64);
            red[j] = t;
        }
        if (l15 == 0) {
            long row = base + rg * 16 + lg * 4;
            if (row < NV) {
                float4 o; o.x = red[0]; o.y = red[1]; o.z = red[2]; o.w = red[3];
                *(float4*)(logitpart + row) = o;
            }
        }
    }
}

// ---------------------------------------------------------------------------
// conv_br: 3 branches; logit = sum_d (bnrelu_d . W_out) + logitpart + b_out
//          att = sigmoid(logit)
// ---------------------------------------------------------------------------
__global__ __launch_bounds__(256, 2)
void conv_br_k(const __bf16* __restrict__ xpad, const int* __restrict__ nbr,
               const __bf16* __restrict__ wpk, const float* __restrict__ scale,
               const float* __restrict__ shiftb, const float* __restrict__ wout,
               const float* __restrict__ bout, const float* __restrict__ logitpart,
               float* __restrict__ att)
{
    const int tid = threadIdx.x;
    const int wid = tid >> 6, lane = tid & 63;
    const int l15 = lane & 15, lg = lane >> 4;
    const long base = (long)blockIdx.x * 256 + wid * 64;

    float wo[4];
#pragma unroll
    for (int cb = 0; cb < 4; cb++) wo[cb] = wout[cb * 16 + l15];

    float lacc[4][4];
#pragma unroll
    for (int rg = 0; rg < 4; rg++)
#pragma unroll
        for (int j = 0; j < 4; j++) lacc[rg][j] = 0.f;

    f32x4 z = {0.f, 0.f, 0.f, 0.f};
    for (int d = 0; d < 3; d++) {
        f32x4 acc[4][4];
#pragma unroll
        for (int a = 0; a < 4; a++)
#pragma unroll
            for (int b = 0; b < 4; b++) acc[a][b] = z;

        for (int k = 0; k < 27; k++)
            conv_tap_accum(xpad, nbr + ((size_t)d * 27 + k) * NV,
                           wpk + ((size_t)((d + 1) * 27 + k)) * 4096,
                           base, l15, lg, lane, acc);

        float sc[4], sh[4];
#pragma unroll
        for (int cb = 0; cb < 4; cb++) {
            int col = (d + 1) * 64 + cb * 16 + l15;
            sc[cb] = scale[col]; sh[cb] = shiftb[col];
        }
#pragma unroll
        for (int rg = 0; rg < 4; rg++)
#pragma unroll
            for (int cb = 0; cb < 4; cb++)
#pragma unroll
                for (int j = 0; j < 4; j++) {
                    float y = fmaxf(acc[rg][cb][j] * sc[cb] + sh[cb], 0.f);
                    lacc[rg][j] += y * wo[cb];
                }
    }

    float bo = bout[0];
#pragma unroll
    for (int rg = 0; rg < 4; rg++) {
        float red[4];
#pragma unroll
        for (int j = 0; j < 4; j++) {
            float t = lacc[rg][j];
            t += __shfl_xor(t, 1, 64);
            t += __shfl_xor(t, 2, 64);
            t += __shfl_xor(t, 4, 64);
            t += __shfl_xor(t, 8, 64);
            red[j] = t;
        }
        if (l15 == 0) {
            long row = base + rg * 16 + lg * 4;
            if (row < NV) {
                float4 lp = *(const float4*)(logitpart + row);
                float4 o;
                o.x = 1.f / (1.f + expf(-(red[0] + lp.x + bo)));
                o.y = 1.f / (1.f + expf(-(red[1] + lp.y + bo)));
                o.z = 1.f / (1.f + expf(-(red[2] + lp.z + bo)));
                o.w = 1.f / (1.f + expf(-(red[3] + lp.w + bo)));
                *(float4*)(att + row) = o;
            }
        }
    }
}

// ---------------------------------------------------------------------------
extern "C" void kernel_launch(void* const* d_in, const int* in_sizes, int n_in,
                              void* d_out, int out_size, void* d_ws, size_t ws_size,
                              hipStream_t stream)
{
    const float* feats  = (const float*)d_in[0];
    const int*   nbr    = (const int*)d_in[1];
    const float* W_init = (const float*)d_in[2];
    const float* b_init = (const float*)d_in[3];
    const float* g_init = (const float*)d_in[4];
    const float* be_init= (const float*)d_in[5];
    const float* m_init = (const float*)d_in[6];
    const float* v_init = (const float*)d_in[7];
    const float* W_br   = (const float*)d_in[8];
    const float* b_br   = (const float*)d_in[9];
    const float* g_br   = (const float*)d_in[10];
    const float* be_br  = (const float*)d_in[11];
    const float* m_br   = (const float*)d_in[12];
    const float* v_br   = (const float*)d_in[13];
    const float* W_out  = (const float*)d_in[14];
    const float* b_out  = (const float*)d_in[15];
    float* att = (float*)d_out;

    char* ws = (char*)d_ws;
    size_t off = 0;
    auto take = [&](size_t bytes) -> char* {
        char* p = ws + off;
        off = (off + bytes + 255) & ~(size_t)255;
        return p;
    };
    __bf16* fpad      = (__bf16*)take((size_t)(NV + 1) * 64 * 2);
    __bf16* xpad      = (__bf16*)take((size_t)(NV + 1) * 64 * 2);
    __bf16* wpk       = (__bf16*)take((size_t)4 * 27 * 4096 * 2);
    float*  scale     = (float*)take(4 * 64 * 4);
    float*  shiftb    = (float*)take(4 * 64 * 4);
    float*  logitpart = (float*)take((size_t)NV * 4);
    (void)in_sizes; (void)n_in; (void)out_size; (void)ws_size;

    prep_feats_k<<<25001, 256, 0, stream>>>(feats, fpad, xpad);
    prep_w_k<<<1728, 256, 0, stream>>>(W_init, W_br, wpk);
    prep_bn_k<<<1, 256, 0, stream>>>(b_init, g_init, be_init, m_init, v_init,
                                     b_br, g_br, be_br, m_br, v_br, scale, shiftb);
    conv_init_k<<<GRID_CONV, 256, 0, stream>>>(fpad, nbr, wpk, scale, shiftb,
                                               W_out, xpad, logitpart);
    conv_br_k<<<GRID_CONV, 256, 0, stream>>>(xpad, nbr, wpk, scale, shiftb,
                                             W_out, b_out, logitpart, att);
}

// Round 2
// 910.814 us; speedup vs baseline: 1.0562x; 1.0562x over previous
//
#include <hip/hip_runtime.h>
#include <hip/hip_bf16.h>
#include <math.h>

#define NV 400000
#define GRID_CONV 1563   // ceil(NV/256)

typedef __bf16 bfv8 __attribute__((ext_vector_type(8)));
typedef float f32x4 __attribute__((ext_vector_type(4)));

// ---------------------------------------------------------------------------
// prep: feats (f32) -> fpad (bf16, N+1 rows, row N = 0); zero xpad row N too
// ---------------------------------------------------------------------------
__global__ void prep_feats_k(const float* __restrict__ feats,
                             __bf16* __restrict__ fpad,
                             __bf16* __restrict__ xpad)
{
    long t = (long)blockIdx.x * blockDim.x + threadIdx.x;
    long base = t * 4;
    const long nfeat = (long)NV * 64;
    const long total = (long)(NV + 1) * 64;
    if (base < total) {
        float x0 = 0.f, x1 = 0.f, x2 = 0.f, x3 = 0.f;
        if (base < nfeat) {
            const float4 v = *(const float4*)(feats + base);
            x0 = v.x; x1 = v.y; x2 = v.z; x3 = v.w;
        }
        union { __bf16 b[4]; ushort4 u; } pk;
        pk.b[0] = (__bf16)x0; pk.b[1] = (__bf16)x1;
        pk.b[2] = (__bf16)x2; pk.b[3] = (__bf16)x3;
        *(ushort4*)(fpad + base) = pk.u;
    }
    if (t < 64) xpad[(long)NV * 64 + t] = (__bf16)0.f;
}

// ---------------------------------------------------------------------------
// prep: pack weights into MFMA B-fragment layout.
// wpk[s][k][kc][cb][lane][i] = W_s[k][cin][cout], cin = kc*32+(lane>>4)*8+i,
// cout = cb*16+(lane&15).  s=0: W_init, s=1..3: W_br[d].
// ---------------------------------------------------------------------------
__global__ void prep_w_k(const float* __restrict__ Winit,
                         const float* __restrict__ Wbr,
                         __bf16* __restrict__ wpk)
{
    int e = blockIdx.x * 256 + threadIdx.x;
    int i  = e & 7;
    int l  = (e >> 3) & 63;
    int cb = (e >> 9) & 3;
    int kc = (e >> 11) & 1;
    int kk = e >> 12;          // s*27 + k
    int k  = kk % 27;
    int s  = kk / 27;
    int cin  = kc * 32 + (l >> 4) * 8 + i;
    int cout = cb * 16 + (l & 15);
    float v = (s == 0) ? Winit[(k * 64 + cin) * 64 + cout]
                       : Wbr[(((s - 1) * 27 + k) * 64 + cin) * 64 + cout];
    wpk[e] = (__bf16)v;
}

// ---------------------------------------------------------------------------
// prep: fold BN (+ conv bias) into scale/shift:  y = conv*sc + sh
// ---------------------------------------------------------------------------
__global__ void prep_bn_k(const float* __restrict__ b_init, const float* __restrict__ g_init,
                          const float* __restrict__ be_init, const float* __restrict__ m_init,
                          const float* __restrict__ v_init,
                          const float* __restrict__ b_br, const float* __restrict__ g_br,
                          const float* __restrict__ be_br, const float* __restrict__ m_br,
                          const float* __restrict__ v_br,
                          float* __restrict__ scale, float* __restrict__ shiftb)
{
    int t = threadIdx.x;          // 0..255
    int s = t >> 6, c = t & 63;
    float g, be, m, v, b;
    if (s == 0) { g = g_init[c]; be = be_init[c]; m = m_init[c]; v = v_init[c]; b = b_init[c]; }
    else { int o = (s - 1) * 64 + c; g = g_br[o]; be = be_br[o]; m = m_br[o]; v = v_br[o]; b = b_br[o]; }
    float sc = g / sqrtf(v + 1e-5f);
    scale[t]  = sc;
    shiftb[t] = (b - m) * sc + be;
}

// ---------------------------------------------------------------------------
// tap helpers
// ---------------------------------------------------------------------------
struct Idx4 { int v[4]; };

__device__ __forceinline__ Idx4 load_idx(const int* __restrict__ nbr_t,
                                         long base, int l15)
{
    Idx4 r;
#pragma unroll
    for (int rg = 0; rg < 4; rg++) {
        long rr = base + rg * 16 + l15;
        rr = (rr < NV) ? rr : (NV - 1);
        r.v[rg] = nbr_t[rr];
    }
    return r;
}

// One tap: B frags first (L2-hot), then 8 independent A gathers, then 32 MFMAs
// ordered so earlier A arrivals can be consumed while later ones are in flight.
__device__ __forceinline__ void tap_mfma(const __bf16* __restrict__ src,
                                         const __bf16* __restrict__ wtap,
                                         const Idx4 idx, int lg, int lane,
                                         f32x4 acc[4][4])
{
    bfv8 bmat[2][4];
    const bfv8* wp = (const bfv8*)wtap;
#pragma unroll
    for (int kc = 0; kc < 2; kc++)
#pragma unroll
        for (int cb = 0; cb < 4; cb++)
            bmat[kc][cb] = wp[(kc * 4 + cb) * 64 + lane];

    bfv8 a0[4], a1[4];
#pragma unroll
    for (int rg = 0; rg < 4; rg++) {
        const bfv8* ar = (const bfv8*)(src + (size_t)idx.v[rg] * 64);
        a0[rg] = ar[lg];
        a1[rg] = ar[4 + lg];
    }
#pragma unroll
    for (int rg = 0; rg < 4; rg++)
#pragma unroll
        for (int cb = 0; cb < 4; cb++) {
            acc[rg][cb] = __builtin_amdgcn_mfma_f32_16x16x32_bf16(a0[rg], bmat[0][cb], acc[rg][cb], 0, 0, 0);
            acc[rg][cb] = __builtin_amdgcn_mfma_f32_16x16x32_bf16(a1[rg], bmat[1][cb], acc[rg][cb], 0, 0, 0);
        }
}

// ---------------------------------------------------------------------------
// conv_init: x_init = bnrelu(conv(fpad, nbr[0..26], W_init)) -> xpad (bf16)
//            + logitpart[row] = x_init[row] . W_out
// ---------------------------------------------------------------------------
__global__ __launch_bounds__(256, 3)
void conv_init_k(const __bf16* __restrict__ fpad, const int* __restrict__ nbr,
                 const __bf16* __restrict__ wpk, const float* __restrict__ scale,
                 const float* __restrict__ shiftb, const float* __restrict__ wout,
                 __bf16* __restrict__ xpad, float* __restrict__ logitpart)
{
    __shared__ __bf16 tile[256 * 64];
    const int tid = threadIdx.x;
    const int wid = tid >> 6, lane = tid & 63;
    const int l15 = lane & 15, lg = lane >> 4;
    const long base = (long)blockIdx.x * 256 + wid * 64;

    f32x4 acc[4][4];
    f32x4 z = {0.f, 0.f, 0.f, 0.f};
#pragma unroll
    for (int a = 0; a < 4; a++)
#pragma unroll
        for (int b = 0; b < 4; b++) acc[a][b] = z;

    Idx4 cur = load_idx(nbr, base, l15);
    for (int k = 0; k < 27; k++) {
        int tn = (k + 1 < 27) ? (k + 1) : 26;
        Idx4 nxt = load_idx(nbr + (size_t)tn * NV, base, l15);
        tap_mfma(fpad, wpk + (size_t)k * 4096, cur, lg, lane, acc);
        cur = nxt;
    }

    float sc[4], sh[4], wo[4];
#pragma unroll
    for (int cb = 0; cb < 4; cb++) {
        int col = cb * 16 + l15;
        sc[cb] = scale[col]; sh[cb] = shiftb[col]; wo[cb] = wout[col];
    }
    float lacc[4][4];
#pragma unroll
    for (int rg = 0; rg < 4; rg++)
#pragma unroll
        for (int j = 0; j < 4; j++) lacc[rg][j] = 0.f;

#pragma unroll
    for (int rg = 0; rg < 4; rg++)
#pragma unroll
        for (int cb = 0; cb < 4; cb++)
#pragma unroll
            for (int j = 0; j < 4; j++) {
                float y = fmaxf(acc[rg][cb][j] * sc[cb] + sh[cb], 0.f);
                lacc[rg][j] += y * wo[cb];
                tile[(wid * 64 + rg * 16 + lg * 4 + j) * 64 + cb * 16 + l15] = (__bf16)y;
            }
    __syncthreads();

    long grow = (long)blockIdx.x * 256 + tid;
    if (grow < NV) {
        const f32x4* srcp = (const f32x4*)(tile + tid * 64);
        f32x4* dst = (f32x4*)(xpad + grow * 64);
#pragma unroll
        for (int q = 0; q < 8; q++) dst[q] = srcp[q];
    }

#pragma unroll
    for (int rg = 0; rg < 4; rg++) {
        float red[4];
#pragma unroll
        for (int j = 0; j < 4; j++) {
            float t = lacc[rg][j];
            t += __shfl_xor(t, 1, 64);
            t += __shfl_xor(t, 2, 64);
            t += __shfl_xor(t, 4, 64);
            t += __shfl_xor(t, 8, 64);
            red[j] = t;
        }
        if (l15 == 0) {
            long row = base + rg * 16 + lg * 4;
            if (row < NV) {
                float4 o; o.x = red[0]; o.y = red[1]; o.z = red[2]; o.w = red[3];
                *(float4*)(logitpart + row) = o;
            }
        }
    }
}

// ---------------------------------------------------------------------------
// conv_br: 3 branches; logit = sum_d (bnrelu_d . W_out) + logitpart + b_out
// ---------------------------------------------------------------------------
__global__ __launch_bounds__(256, 3)
void conv_br_k(const __bf16* __restrict__ xpad, const int* __restrict__ nbr,
               const __bf16* __restrict__ wpk, const float* __restrict__ scale,
               const float* __restrict__ shiftb, const float* __restrict__ wout,
               const float* __restrict__ bout, const float* __restrict__ logitpart,
               float* __restrict__ att)
{
    const int tid = threadIdx.x;
    const int wid = tid >> 6, lane = tid & 63;
    const int l15 = lane & 15, lg = lane >> 4;
    const long base = (long)blockIdx.x * 256 + wid * 64;

    float wo[4];
#pragma unroll
    for (int cb = 0; cb < 4; cb++) wo[cb] = wout[cb * 16 + l15];

    float lacc[4][4];
#pragma unroll
    for (int rg = 0; rg < 4; rg++)
#pragma unroll
        for (int j = 0; j < 4; j++) lacc[rg][j] = 0.f;

    f32x4 z = {0.f, 0.f, 0.f, 0.f};
    Idx4 cur = load_idx(nbr, base, l15);
    for (int d = 0; d < 3; d++) {
        f32x4 acc[4][4];
#pragma unroll
        for (int a = 0; a < 4; a++)
#pragma unroll
            for (int b = 0; b < 4; b++) acc[a][b] = z;

        for (int k = 0; k < 27; k++) {
            int t = d * 27 + k;
            int tn = (t + 1 < 81) ? (t + 1) : 80;
            Idx4 nxt = load_idx(nbr + (size_t)tn * NV, base, l15);
            tap_mfma(xpad, wpk + (size_t)(t + 27) * 4096, cur, lg, lane, acc);
            cur = nxt;
        }

        float sc[4], sh[4];
#pragma unroll
        for (int cb = 0; cb < 4; cb++) {
            int col = (d + 1) * 64 + cb * 16 + l15;
            sc[cb] = scale[col]; sh[cb] = shiftb[col];
        }
#pragma unroll
        for (int rg = 0; rg < 4; rg++)
#pragma unroll
            for (int cb = 0; cb < 4; cb++)
#pragma unroll
                for (int j = 0; j < 4; j++) {
                    float y = fmaxf(acc[rg][cb][j] * sc[cb] + sh[cb], 0.f);
                    lacc[rg][j] += y * wo[cb];
                }
    }

    float bo = bout[0];
#pragma unroll
    for (int rg = 0; rg < 4; rg++) {
        float red[4];
#pragma unroll
        for (int j = 0; j < 4; j++) {
            float t = lacc[rg][j];
            t += __shfl_xor(t, 1, 64);
            t += __shfl_xor(t, 2, 64);
            t += __shfl_xor(t, 4, 64);
            t += __shfl_xor(t, 8, 64);
            red[j] = t;
        }
        if (l15 == 0) {
            long row = base + rg * 16 + lg * 4;
            if (row < NV) {
                float4 lp = *(const float4*)(logitpart + row);
                float4 o;
                o.x = 1.f / (1.f + expf(-(red[0] + lp.x + bo)));
                o.y = 1.f / (1.f + expf(-(red[1] + lp.y + bo)));
                o.z = 1.f / (1.f + expf(-(red[2] + lp.z + bo)));
                o.w = 1.f / (1.f + expf(-(red[3] + lp.w + bo)));
                *(float4*)(att + row) = o;
            }
        }
    }
}

// ---------------------------------------------------------------------------
extern "C" void kernel_launch(void* const* d_in, const int* in_sizes, int n_in,
                              void* d_out, int out_size, void* d_ws, size_t ws_size,
                              hipStream_t stream)
{
    const float* feats  = (const float*)d_in[0];
    const int*   nbr    = (const int*)d_in[1];
    const float* W_init = (const float*)d_in[2];
    const float* b_init = (const float*)d_in[3];
    const float* g_init = (const float*)d_in[4];
    const float* be_init= (const float*)d_in[5];
    const float* m_init = (const float*)d_in[6];
    const float* v_init = (const float*)d_in[7];
    const float* W_br   = (const float*)d_in[8];
    const float* b_br   = (const float*)d_in[9];
    const float* g_br   = (const float*)d_in[10];
    const float* be_br  = (const float*)d_in[11];
    const float* m_br   = (const float*)d_in[12];
    const float* v_br   = (const float*)d_in[13];
    const float* W_out  = (const float*)d_in[14];
    const float* b_out  = (const float*)d_in[15];
    float* att = (float*)d_out;

    char* ws = (char*)d_ws;
    size_t off = 0;
    auto take = [&](size_t bytes) -> char* {
        char* p = ws + off;
        off = (off + bytes + 255) & ~(size_t)255;
        return p;
    };
    __bf16* fpad      = (__bf16*)take((size_t)(NV + 1) * 64 * 2);
    __bf16* xpad      = (__bf16*)take((size_t)(NV + 1) * 64 * 2);
    __bf16* wpk       = (__bf16*)take((size_t)4 * 27 * 4096 * 2);
    float*  scale     = (float*)take(4 * 64 * 4);
    float*  shiftb    = (float*)take(4 * 64 * 4);
    float*  logitpart = (float*)take((size_t)NV * 4);
    (void)in_sizes; (void)n_in; (void)out_size; (void)ws_size;

    prep_feats_k<<<25001, 256, 0, stream>>>(feats, fpad, xpad);
    prep_w_k<<<1728, 256, 0, stream>>>(W_init, W_br, wpk);
    prep_bn_k<<<1, 256, 0, stream>>>(b_init, g_init, be_init, m_init, v_init,
                                     b_br, g_br, be_br, m_br, v_br, scale, shiftb);
    conv_init_k<<<GRID_CONV, 256, 0, stream>>>(fpad, nbr, wpk, scale, shiftb,
                                               W_out, xpad, logitpart);
    conv_br_k<<<GRID_CONV, 256, 0, stream>>>(xpad, nbr, wpk, scale, shiftb,
                                             W_out, b_out, logitpart, att);
}

// Round 3
// 698.437 us; speedup vs baseline: 1.3773x; 1.3041x over previous
//
#include <hip/hip_runtime.h>
#include <hip/hip_bf16.h>
#include <math.h>

#define NV 400000
#define GRID_CONV 1563   // ceil(NV/256)

typedef __bf16 bfv8 __attribute__((ext_vector_type(8)));
typedef float f32x4 __attribute__((ext_vector_type(4)));

// async global->LDS staging, 16B per lane
#define GLOAD_LDS16(gp, lp) __builtin_amdgcn_global_load_lds(                 \
    (const __attribute__((address_space(1))) void*)(gp),                     \
    (__attribute__((address_space(3))) void*)(lp), 16, 0, 0)

// ---------------------------------------------------------------------------
// prep: feats (f32) -> fpad (bf16, N+1 rows, row N = 0); zero xpad row N too
// ---------------------------------------------------------------------------
__global__ void prep_feats_k(const float* __restrict__ feats,
                             __bf16* __restrict__ fpad,
                             __bf16* __restrict__ xpad)
{
    long t = (long)blockIdx.x * blockDim.x + threadIdx.x;
    long base = t * 4;
    const long nfeat = (long)NV * 64;
    const long total = (long)(NV + 1) * 64;
    if (base < total) {
        float x0 = 0.f, x1 = 0.f, x2 = 0.f, x3 = 0.f;
        if (base < nfeat) {
            const float4 v = *(const float4*)(feats + base);
            x0 = v.x; x1 = v.y; x2 = v.z; x3 = v.w;
        }
        union { __bf16 b[4]; ushort4 u; } pk;
        pk.b[0] = (__bf16)x0; pk.b[1] = (__bf16)x1;
        pk.b[2] = (__bf16)x2; pk.b[3] = (__bf16)x3;
        *(ushort4*)(fpad + base) = pk.u;
    }
    if (t < 64) xpad[(long)NV * 64 + t] = (__bf16)0.f;
}

// ---------------------------------------------------------------------------
// prep: pack weights into MFMA B-fragment layout.
// wpk[s][k][kc][cb][lane][i] = W_s[k][cin][cout], cin = kc*32+(lane>>4)*8+i,
// cout = cb*16+(lane&15).  s=0: W_init, s=1..3: W_br[d].
// ---------------------------------------------------------------------------
__global__ void prep_w_k(const float* __restrict__ Winit,
                         const float* __restrict__ Wbr,
                         __bf16* __restrict__ wpk)
{
    int e = blockIdx.x * 256 + threadIdx.x;
    int i  = e & 7;
    int l  = (e >> 3) & 63;
    int cb = (e >> 9) & 3;
    int kc = (e >> 11) & 1;
    int kk = e >> 12;          // s*27 + k
    int k  = kk % 27;
    int s  = kk / 27;
    int cin  = kc * 32 + (l >> 4) * 8 + i;
    int cout = cb * 16 + (l & 15);
    float v = (s == 0) ? Winit[(k * 64 + cin) * 64 + cout]
                       : Wbr[(((s - 1) * 27 + k) * 64 + cin) * 64 + cout];
    wpk[e] = (__bf16)v;
}

// ---------------------------------------------------------------------------
// prep: fold BN (+ conv bias) into scale/shift:  y = conv*sc + sh
// ---------------------------------------------------------------------------
__global__ void prep_bn_k(const float* __restrict__ b_init, const float* __restrict__ g_init,
                          const float* __restrict__ be_init, const float* __restrict__ m_init,
                          const float* __restrict__ v_init,
                          const float* __restrict__ b_br, const float* __restrict__ g_br,
                          const float* __restrict__ be_br, const float* __restrict__ m_br,
                          const float* __restrict__ v_br,
                          float* __restrict__ scale, float* __restrict__ shiftb)
{
    int t = threadIdx.x;          // 0..255
    int s = t >> 6, c = t & 63;
    float g, be, m, v, b;
    if (s == 0) { g = g_init[c]; be = be_init[c]; m = m_init[c]; v = v_init[c]; b = b_init[c]; }
    else { int o = (s - 1) * 64 + c; g = g_br[o]; be = be_br[o]; m = m_br[o]; v = v_br[o]; b = b_br[o]; }
    float sc = g / sqrtf(v + 1e-5f);
    scale[t]  = sc;
    shiftb[t] = (b - m) * sc + be;
}

// ---------------------------------------------------------------------------
// tap helpers
// ---------------------------------------------------------------------------
struct Idx4 { int v[4]; };

__device__ __forceinline__ Idx4 load_idx(const int* __restrict__ nbr_t,
                                         long base, int l15)
{
    Idx4 r;
#pragma unroll
    for (int rg = 0; rg < 4; rg++) {
        long rr = base + rg * 16 + l15;
        rr = (rr < NV) ? rr : (NV - 1);
        r.v[rg] = nbr_t[rr];
    }
    return r;
}

// stage one tap's packed B (8 KB) into LDS; wave wid covers chunks 2w,2w+1
__device__ __forceinline__ void stage_b(const __bf16* __restrict__ wtap,
                                        __bf16* lds_dst, int wid, int lane)
{
#pragma unroll
    for (int j = 0; j < 2; j++) {
        int chunk = wid * 2 + j;
        const __bf16* gp = wtap + chunk * 512 + lane * 8;  // per-lane global src
        __bf16* lp = lds_dst + chunk * 512;                // wave-uniform LDS base
        GLOAD_LDS16(gp, lp);
    }
}

// One tap: A gathers from global (divergent, 16 lines/instr), B frags from LDS.
// B read just-in-time so only 1-2 frags live -> low VGPR pressure.
__device__ __forceinline__ void tap_mfma_lds(const __bf16* __restrict__ src,
                                             const __bf16* bbuf, // LDS, 4096 bf16
                                             const Idx4 idx, int lg, int lane,
                                             f32x4 acc[4][4])
{
    bfv8 a0[4], a1[4];
#pragma unroll
    for (int rg = 0; rg < 4; rg++) {
        const bfv8* ar = (const bfv8*)(src + (size_t)idx.v[rg] * 64);
        a0[rg] = ar[lg];       // k = 0..31
        a1[rg] = ar[4 + lg];   // k = 32..63
    }
    const bfv8* wp = (const bfv8*)bbuf;
#pragma unroll
    for (int cb = 0; cb < 4; cb++) {
        bfv8 b0 = wp[cb * 64 + lane];
#pragma unroll
        for (int rg = 0; rg < 4; rg++)
            acc[rg][cb] = __builtin_amdgcn_mfma_f32_16x16x32_bf16(a0[rg], b0, acc[rg][cb], 0, 0, 0);
    }
#pragma unroll
    for (int cb = 0; cb < 4; cb++) {
        bfv8 b1 = wp[(4 + cb) * 64 + lane];
#pragma unroll
        for (int rg = 0; rg < 4; rg++)
            acc[rg][cb] = __builtin_amdgcn_mfma_f32_16x16x32_bf16(a1[rg], b1, acc[rg][cb], 0, 0, 0);
    }
}

// ---------------------------------------------------------------------------
// conv_init: x_init = bnrelu(conv(fpad, nbr[0..26], W_init)) -> xpad (bf16)
//            + logitpart[row] = x_init[row] . W_out
// ---------------------------------------------------------------------------
__global__ __launch_bounds__(256, 3)
void conv_init_k(const __bf16* __restrict__ fpad, const int* __restrict__ nbr,
                 const __bf16* __restrict__ wpk, const float* __restrict__ scale,
                 const float* __restrict__ shiftb, const float* __restrict__ wout,
                 __bf16* __restrict__ xpad, float* __restrict__ logitpart)
{
    __shared__ __bf16 tile[256 * 64];
    __shared__ __bf16 bbuf[2][4096];
    const int tid = threadIdx.x;
    const int wid = tid >> 6, lane = tid & 63;
    const int l15 = lane & 15, lg = lane >> 4;
    const long base = (long)blockIdx.x * 256 + wid * 64;

    f32x4 acc[4][4];
    f32x4 z = {0.f, 0.f, 0.f, 0.f};
#pragma unroll
    for (int a = 0; a < 4; a++)
#pragma unroll
        for (int b = 0; b < 4; b++) acc[a][b] = z;

    Idx4 cur = load_idx(nbr, base, l15);
    stage_b(wpk, bbuf[0], wid, lane);
    __syncthreads();

    for (int k = 0; k < 27; k++) {
        if (k + 1 < 27)
            stage_b(wpk + (size_t)(k + 1) * 4096, bbuf[(k + 1) & 1], wid, lane);
        int tn = (k + 1 < 27) ? (k + 1) : 26;
        Idx4 nxt = load_idx(nbr + (size_t)tn * NV, base, l15);
        tap_mfma_lds(fpad, bbuf[k & 1], cur, lg, lane, acc);
        __syncthreads();
        cur = nxt;
    }

    float sc[4], sh[4], wo[4];
#pragma unroll
    for (int cb = 0; cb < 4; cb++) {
        int col = cb * 16 + l15;
        sc[cb] = scale[col]; sh[cb] = shiftb[col]; wo[cb] = wout[col];
    }
    float lacc[4][4];
#pragma unroll
    for (int rg = 0; rg < 4; rg++)
#pragma unroll
        for (int j = 0; j < 4; j++) lacc[rg][j] = 0.f;

#pragma unroll
    for (int rg = 0; rg < 4; rg++)
#pragma unroll
        for (int cb = 0; cb < 4; cb++)
#pragma unroll
            for (int j = 0; j < 4; j++) {
                float y = fmaxf(acc[rg][cb][j] * sc[cb] + sh[cb], 0.f);
                lacc[rg][j] += y * wo[cb];
                tile[(wid * 64 + rg * 16 + lg * 4 + j) * 64 + cb * 16 + l15] = (__bf16)y;
            }
    __syncthreads();

    long grow = (long)blockIdx.x * 256 + tid;
    if (grow < NV) {
        const f32x4* srcp = (const f32x4*)(tile + tid * 64);
        f32x4* dst = (f32x4*)(xpad + grow * 64);
#pragma unroll
        for (int q = 0; q < 8; q++) dst[q] = srcp[q];
    }

#pragma unroll
    for (int rg = 0; rg < 4; rg++) {
        float red[4];
#pragma unroll
        for (int j = 0; j < 4; j++) {
            float t = lacc[rg][j];
            t += __shfl_xor(t, 1, 64);
            t += __shfl_xor(t, 2, 64);
            t += __shfl_xor(t, 4, 64);
            t += __shfl_xor(t, 8, 64);
            red[j] = t;
        }
        if (l15 == 0) {
            long row = base + rg * 16 + lg * 4;
            if (row < NV) {
                float4 o; o.x = red[0]; o.y = red[1]; o.z = red[2]; o.w = red[3];
                *(float4*)(logitpart + row) = o;
            }
        }
    }
}

// ---------------------------------------------------------------------------
// conv_br: 3 branches; logit = sum_d (bnrelu_d . W_out) + logitpart + b_out
// ---------------------------------------------------------------------------
__global__ __launch_bounds__(256, 3)
void conv_br_k(const __bf16* __restrict__ xpad, const int* __restrict__ nbr,
               const __bf16* __restrict__ wpk, const float* __restrict__ scale,
               const float* __restrict__ shiftb, const float* __restrict__ wout,
               const float* __restrict__ bout, const float* __restrict__ logitpart,
               float* __restrict__ att)
{
    __shared__ __bf16 bbuf[2][4096];
    const int tid = threadIdx.x;
    const int wid = tid >> 6, lane = tid & 63;
    const int l15 = lane & 15, lg = lane >> 4;
    const long base = (long)blockIdx.x * 256 + wid * 64;

    float wo[4];
#pragma unroll
    for (int cb = 0; cb < 4; cb++) wo[cb] = wout[cb * 16 + l15];

    float lacc[4][4];
#pragma unroll
    for (int rg = 0; rg < 4; rg++)
#pragma unroll
        for (int j = 0; j < 4; j++) lacc[rg][j] = 0.f;

    f32x4 z = {0.f, 0.f, 0.f, 0.f};
    Idx4 cur = load_idx(nbr, base, l15);
    stage_b(wpk + (size_t)27 * 4096, bbuf[0], wid, lane);  // branch 0, tap 0
    __syncthreads();

    for (int d = 0; d < 3; d++) {
        f32x4 acc[4][4];
#pragma unroll
        for (int a = 0; a < 4; a++)
#pragma unroll
            for (int b = 0; b < 4; b++) acc[a][b] = z;

        for (int k = 0; k < 27; k++) {
            int t = d * 27 + k;
            if (t + 1 < 81)
                stage_b(wpk + (size_t)(t + 1 + 27) * 4096, bbuf[(t + 1) & 1], wid, lane);
            int tn = (t + 1 < 81) ? (t + 1) : 80;
            Idx4 nxt = load_idx(nbr + (size_t)tn * NV, base, l15);
            tap_mfma_lds(xpad, bbuf[t & 1], cur, lg, lane, acc);
            __syncthreads();
            cur = nxt;
        }

        float sc[4], sh[4];
#pragma unroll
        for (int cb = 0; cb < 4; cb++) {
            int col = (d + 1) * 64 + cb * 16 + l15;
            sc[cb] = scale[col]; sh[cb] = shiftb[col];
        }
#pragma unroll
        for (int rg = 0; rg < 4; rg++)
#pragma unroll
            for (int cb = 0; cb < 4; cb++)
#pragma unroll
                for (int j = 0; j < 4; j++) {
                    float y = fmaxf(acc[rg][cb][j] * sc[cb] + sh[cb], 0.f);
                    lacc[rg][j] += y * wo[cb];
                }
    }

    float bo = bout[0];
#pragma unroll
    for (int rg = 0; rg < 4; rg++) {
        float red[4];
#pragma unroll
        for (int j = 0; j < 4; j++) {
            float t = lacc[rg][j];
            t += __shfl_xor(t, 1, 64);
            t += __shfl_xor(t, 2, 64);
            t += __shfl_xor(t, 4, 64);
            t += __shfl_xor(t, 8, 64);
            red[j] = t;
        }
        if (l15 == 0) {
            long row = base + rg * 16 + lg * 4;
            if (row < NV) {
                float4 lp = *(const float4*)(logitpart + row);
                float4 o;
                o.x = 1.f / (1.f + expf(-(red[0] + lp.x + bo)));
                o.y = 1.f / (1.f + expf(-(red[1] + lp.y + bo)));
                o.z = 1.f / (1.f + expf(-(red[2] + lp.z + bo)));
                o.w = 1.f / (1.f + expf(-(red[3] + lp.w + bo)));
                *(float4*)(att + row) = o;
            }
        }
    }
}

// ---------------------------------------------------------------------------
extern "C" void kernel_launch(void* const* d_in, const int* in_sizes, int n_in,
                              void* d_out, int out_size, void* d_ws, size_t ws_size,
                              hipStream_t stream)
{
    const float* feats  = (const float*)d_in[0];
    const int*   nbr    = (const int*)d_in[1];
    const float* W_init = (const float*)d_in[2];
    const float* b_init = (const float*)d_in[3];
    const float* g_init = (const float*)d_in[4];
    const float* be_init= (const float*)d_in[5];
    const float* m_init = (const float*)d_in[6];
    const float* v_init = (const float*)d_in[7];
    const float* W_br   = (const float*)d_in[8];
    const float* b_br   = (const float*)d_in[9];
    const float* g_br   = (const float*)d_in[10];
    const float* be_br  = (const float*)d_in[11];
    const float* m_br   = (const float*)d_in[12];
    const float* v_br   = (const float*)d_in[13];
    const float* W_out  = (const float*)d_in[14];
    const float* b_out  = (const float*)d_in[15];
    float* att = (float*)d_out;

    char* ws = (char*)d_ws;
    size_t off = 0;
    auto take = [&](size_t bytes) -> char* {
        char* p = ws + off;
        off = (off + bytes + 255) & ~(size_t)255;
        return p;
    };
    __bf16* fpad      = (__bf16*)take((size_t)(NV + 1) * 64 * 2);
    __bf16* xpad      = (__bf16*)take((size_t)(NV + 1) * 64 * 2);
    __bf16* wpk       = (__bf16*)take((size_t)4 * 27 * 4096 * 2);
    float*  scale     = (float*)take(4 * 64 * 4);
    float*  shiftb    = (float*)take(4 * 64 * 4);
    float*  logitpart = (float*)take((size_t)NV * 4);
    (void)in_sizes; (void)n_in; (void)out_size; (void)ws_size;

    prep_feats_k<<<25001, 256, 0, stream>>>(feats, fpad, xpad);
    prep_w_k<<<1728, 256, 0, stream>>>(W_init, W_br, wpk);
    prep_bn_k<<<1, 256, 0, stream>>>(b_init, g_init, be_init, m_init, v_init,
                                     b_br, g_br, be_br, m_br, v_br, scale, shiftb);
    conv_init_k<<<GRID_CONV, 256, 0, stream>>>(fpad, nbr, wpk, scale, shiftb,
                                               W_out, xpad, logitpart);
    conv_br_k<<<GRID_CONV, 256, 0, stream>>>(xpad, nbr, wpk, scale, shiftb,
                                             W_out, b_out, logitpart, att);
}

// Round 4
// 595.373 us; speedup vs baseline: 1.6158x; 1.1731x over previous
//
#include <hip/hip_runtime.h>
#include <hip/hip_bf16.h>
#include <math.h>

#define NV 400000
#define ROWS_BLK 128
#define GRID_CONV 3125   // NV / 128 exactly

typedef __bf16 bfv8 __attribute__((ext_vector_type(8)));
typedef float f32x4 __attribute__((ext_vector_type(4)));

// async global->LDS staging, 16B per lane
#define GLOAD_LDS16(gp, lp) __builtin_amdgcn_global_load_lds(                 \
    (const __attribute__((address_space(1))) void*)(gp),                     \
    (__attribute__((address_space(3))) void*)(lp), 16, 0, 0)

// ---------------------------------------------------------------------------
// prep: feats (f32) -> fpad (bf16, N+1 rows, row N = 0); zero xpad row N too
// ---------------------------------------------------------------------------
__global__ void prep_feats_k(const float* __restrict__ feats,
                             __bf16* __restrict__ fpad,
                             __bf16* __restrict__ xpad)
{
    long t = (long)blockIdx.x * blockDim.x + threadIdx.x;
    long base = t * 4;
    const long nfeat = (long)NV * 64;
    const long total = (long)(NV + 1) * 64;
    if (base < total) {
        float x0 = 0.f, x1 = 0.f, x2 = 0.f, x3 = 0.f;
        if (base < nfeat) {
            const float4 v = *(const float4*)(feats + base);
            x0 = v.x; x1 = v.y; x2 = v.z; x3 = v.w;
        }
        union { __bf16 b[4]; ushort4 u; } pk;
        pk.b[0] = (__bf16)x0; pk.b[1] = (__bf16)x1;
        pk.b[2] = (__bf16)x2; pk.b[3] = (__bf16)x3;
        *(ushort4*)(fpad + base) = pk.u;
    }
    if (t < 64) xpad[(long)NV * 64 + t] = (__bf16)0.f;
}

// ---------------------------------------------------------------------------
// prep: pack weights into MFMA B-fragment layout.
// wpk[s][k][kc][cb][lane][i] = W_s[k][cin][cout], cin = kc*32+(lane>>4)*8+i,
// cout = cb*16+(lane&15).  s=0: W_init, s=1..3: W_br[d].
// ---------------------------------------------------------------------------
__global__ void prep_w_k(const float* __restrict__ Winit,
                         const float* __restrict__ Wbr,
                         __bf16* __restrict__ wpk)
{
    int e = blockIdx.x * 256 + threadIdx.x;
    int i  = e & 7;
    int l  = (e >> 3) & 63;
    int cb = (e >> 9) & 3;
    int kc = (e >> 11) & 1;
    int kk = e >> 12;          // s*27 + k
    int k  = kk % 27;
    int s  = kk / 27;
    int cin  = kc * 32 + (l >> 4) * 8 + i;
    int cout = cb * 16 + (l & 15);
    float v = (s == 0) ? Winit[(k * 64 + cin) * 64 + cout]
                       : Wbr[(((s - 1) * 27 + k) * 64 + cin) * 64 + cout];
    wpk[e] = (__bf16)v;
}

// ---------------------------------------------------------------------------
// prep: fold BN (+ conv bias) into scale/shift:  y = conv*sc + sh
// ---------------------------------------------------------------------------
__global__ void prep_bn_k(const float* __restrict__ b_init, const float* __restrict__ g_init,
                          const float* __restrict__ be_init, const float* __restrict__ m_init,
                          const float* __restrict__ v_init,
                          const float* __restrict__ b_br, const float* __restrict__ g_br,
                          const float* __restrict__ be_br, const float* __restrict__ m_br,
                          const float* __restrict__ v_br,
                          float* __restrict__ scale, float* __restrict__ shiftb)
{
    int t = threadIdx.x;          // 0..255
    int s = t >> 6, c = t & 63;
    float g, be, m, v, b;
    if (s == 0) { g = g_init[c]; be = be_init[c]; m = m_init[c]; v = v_init[c]; b = b_init[c]; }
    else { int o = (s - 1) * 64 + c; g = g_br[o]; be = be_br[o]; m = m_br[o]; v = v_br[o]; b = b_br[o]; }
    float sc = g / sqrtf(v + 1e-5f);
    scale[t]  = sc;
    shiftb[t] = (b - m) * sc + be;
}

// ---------------------------------------------------------------------------
// tap helpers — 32 rows per wave (2 row-groups of 16)
// ---------------------------------------------------------------------------
struct Idx2 { int v[2]; };

__device__ __forceinline__ Idx2 load_idx(const int* __restrict__ nbr_t,
                                         long base, int l15)
{
    Idx2 r;
#pragma unroll
    for (int rg = 0; rg < 2; rg++) {
        long rr = base + rg * 16 + l15;
        rr = (rr < NV) ? rr : (NV - 1);
        r.v[rg] = nbr_t[rr];
    }
    return r;
}

// stage one tap's packed B (8 KB = 4096 bf16) into LDS; 8 chunks, 4 waves x 2
__device__ __forceinline__ void stage_b(const __bf16* __restrict__ wtap,
                                        __bf16* lds_dst, int wid, int lane)
{
#pragma unroll
    for (int j = 0; j < 2; j++) {
        int chunk = wid * 2 + j;
        const __bf16* gp = wtap + chunk * 512 + lane * 8;  // per-lane global src
        __bf16* lp = lds_dst + chunk * 512;                // wave-uniform LDS base
        GLOAD_LDS16(gp, lp);
    }
}

// One tap: A gathers from global (divergent), B frags JIT from LDS.
__device__ __forceinline__ void tap_mfma_lds(const __bf16* __restrict__ src,
                                             const __bf16* bbuf, // LDS, 4096 bf16
                                             const Idx2 idx, int lg, int lane,
                                             f32x4 acc[2][4])
{
    bfv8 a0[2], a1[2];
#pragma unroll
    for (int rg = 0; rg < 2; rg++) {
        const bfv8* ar = (const bfv8*)(src + (size_t)idx.v[rg] * 64);
        a0[rg] = ar[lg];       // k = 0..31
        a1[rg] = ar[4 + lg];   // k = 32..63
    }
    const bfv8* wp = (const bfv8*)bbuf;
#pragma unroll
    for (int cb = 0; cb < 4; cb++) {
        bfv8 b0 = wp[cb * 64 + lane];
#pragma unroll
        for (int rg = 0; rg < 2; rg++)
            acc[rg][cb] = __builtin_amdgcn_mfma_f32_16x16x32_bf16(a0[rg], b0, acc[rg][cb], 0, 0, 0);
    }
#pragma unroll
    for (int cb = 0; cb < 4; cb++) {
        bfv8 b1 = wp[(4 + cb) * 64 + lane];
#pragma unroll
        for (int rg = 0; rg < 2; rg++)
            acc[rg][cb] = __builtin_amdgcn_mfma_f32_16x16x32_bf16(a1[rg], b1, acc[rg][cb], 0, 0, 0);
    }
}

// ---------------------------------------------------------------------------
// conv_init: x_init = bnrelu(conv(fpad, nbr[0..26], W_init)) -> xpad (bf16)
//            + logitpart[row] = x_init[row] . W_out
// ---------------------------------------------------------------------------
__global__ __launch_bounds__(256, 4)
void conv_init_k(const __bf16* __restrict__ fpad, const int* __restrict__ nbr,
                 const __bf16* __restrict__ wpk, const float* __restrict__ scale,
                 const float* __restrict__ shiftb, const float* __restrict__ wout,
                 __bf16* __restrict__ xpad, float* __restrict__ logitpart)
{
    __shared__ __bf16 tile[ROWS_BLK * 64];
    __shared__ __bf16 bbuf[2][4096];
    const int tid = threadIdx.x;
    const int wid = tid >> 6, lane = tid & 63;
    const int l15 = lane & 15, lg = lane >> 4;
    const long base = (long)blockIdx.x * ROWS_BLK + wid * 32;

    f32x4 acc[2][4];
    f32x4 z = {0.f, 0.f, 0.f, 0.f};
#pragma unroll
    for (int a = 0; a < 2; a++)
#pragma unroll
        for (int b = 0; b < 4; b++) acc[a][b] = z;

    Idx2 cur = load_idx(nbr, base, l15);
    stage_b(wpk, bbuf[0], wid, lane);
    __syncthreads();

    for (int k = 0; k < 27; k++) {
        if (k + 1 < 27)
            stage_b(wpk + (size_t)(k + 1) * 4096, bbuf[(k + 1) & 1], wid, lane);
        int tn = (k + 1 < 27) ? (k + 1) : 26;
        Idx2 nxt = load_idx(nbr + (size_t)tn * NV, base, l15);
        tap_mfma_lds(fpad, bbuf[k & 1], cur, lg, lane, acc);
        __syncthreads();
        cur = nxt;
    }

    float sc[4], sh[4], wo[4];
#pragma unroll
    for (int cb = 0; cb < 4; cb++) {
        int col = cb * 16 + l15;
        sc[cb] = scale[col]; sh[cb] = shiftb[col]; wo[cb] = wout[col];
    }
    float lacc[2][4];
#pragma unroll
    for (int rg = 0; rg < 2; rg++)
#pragma unroll
        for (int j = 0; j < 4; j++) lacc[rg][j] = 0.f;

#pragma unroll
    for (int rg = 0; rg < 2; rg++)
#pragma unroll
        for (int cb = 0; cb < 4; cb++)
#pragma unroll
            for (int j = 0; j < 4; j++) {
                float y = fmaxf(acc[rg][cb][j] * sc[cb] + sh[cb], 0.f);
                lacc[rg][j] += y * wo[cb];
                tile[(wid * 32 + rg * 16 + lg * 4 + j) * 64 + cb * 16 + l15] = (__bf16)y;
            }
    __syncthreads();

    // coalesced write: 2 threads per row, 64B each
    {
        int r = tid >> 1, h = tid & 1;
        long grow = (long)blockIdx.x * ROWS_BLK + r;
        const f32x4* srcp = (const f32x4*)(tile + r * 64 + h * 32);
        f32x4* dst = (f32x4*)(xpad + grow * 64 + h * 32);
#pragma unroll
        for (int q = 0; q < 4; q++) dst[q] = srcp[q];
    }

#pragma unroll
    for (int rg = 0; rg < 2; rg++) {
        float red[4];
#pragma unroll
        for (int j = 0; j < 4; j++) {
            float t = lacc[rg][j];
            t += __shfl_xor(t, 1, 64);
            t += __shfl_xor(t, 2, 64);
            t += __shfl_xor(t, 4, 64);
            t += __shfl_xor(t, 8, 64);
            red[j] = t;
        }
        if (l15 == 0) {
            long row = base + rg * 16 + lg * 4;
            float4 o; o.x = red[0]; o.y = red[1]; o.z = red[2]; o.w = red[3];
            *(float4*)(logitpart + row) = o;
        }
    }
}

// ---------------------------------------------------------------------------
// conv_br: 3 branches; logit = sum_d (bnrelu_d . W_out) + logitpart + b_out
// ---------------------------------------------------------------------------
__global__ __launch_bounds__(256, 4)
void conv_br_k(const __bf16* __restrict__ xpad, const int* __restrict__ nbr,
               const __bf16* __restrict__ wpk, const float* __restrict__ scale,
               const float* __restrict__ shiftb, const float* __restrict__ wout,
               const float* __restrict__ bout, const float* __restrict__ logitpart,
               float* __restrict__ att)
{
    __shared__ __bf16 bbuf[2][4096];
    const int tid = threadIdx.x;
    const int wid = tid >> 6, lane = tid & 63;
    const int l15 = lane & 15, lg = lane >> 4;
    const long base = (long)blockIdx.x * ROWS_BLK + wid * 32;

    float wo[4];
#pragma unroll
    for (int cb = 0; cb < 4; cb++) wo[cb] = wout[cb * 16 + l15];

    float lacc[2][4];
#pragma unroll
    for (int rg = 0; rg < 2; rg++)
#pragma unroll
        for (int j = 0; j < 4; j++) lacc[rg][j] = 0.f;

    f32x4 z = {0.f, 0.f, 0.f, 0.f};
    Idx2 cur = load_idx(nbr, base, l15);
    stage_b(wpk + (size_t)27 * 4096, bbuf[0], wid, lane);  // branch 0, tap 0
    __syncthreads();

    for (int d = 0; d < 3; d++) {
        f32x4 acc[2][4];
#pragma unroll
        for (int a = 0; a < 2; a++)
#pragma unroll
            for (int b = 0; b < 4; b++) acc[a][b] = z;

        for (int k = 0; k < 27; k++) {
            int t = d * 27 + k;
            if (t + 1 < 81)
                stage_b(wpk + (size_t)(t + 1 + 27) * 4096, bbuf[(t + 1) & 1], wid, lane);
            int tn = (t + 1 < 81) ? (t + 1) : 80;
            Idx2 nxt = load_idx(nbr + (size_t)tn * NV, base, l15);
            tap_mfma_lds(xpad, bbuf[t & 1], cur, lg, lane, acc);
            __syncthreads();
            cur = nxt;
        }

        float sc[4], sh[4];
#pragma unroll
        for (int cb = 0; cb < 4; cb++) {
            int col = (d + 1) * 64 + cb * 16 + l15;
            sc[cb] = scale[col]; sh[cb] = shiftb[col];
        }
#pragma unroll
        for (int rg = 0; rg < 2; rg++)
#pragma unroll
            for (int cb = 0; cb < 4; cb++)
#pragma unroll
                for (int j = 0; j < 4; j++) {
                    float y = fmaxf(acc[rg][cb][j] * sc[cb] + sh[cb], 0.f);
                    lacc[rg][j] += y * wo[cb];
                }
    }

    float bo = bout[0];
#pragma unroll
    for (int rg = 0; rg < 2; rg++) {
        float red[4];
#pragma unroll
        for (int j = 0; j < 4; j++) {
            float t = lacc[rg][j];
            t += __shfl_xor(t, 1, 64);
            t += __shfl_xor(t, 2, 64);
            t += __shfl_xor(t, 4, 64);
            t += __shfl_xor(t, 8, 64);
            red[j] = t;
        }
        if (l15 == 0) {
            long row = base + rg * 16 + lg * 4;
            float4 lp = *(const float4*)(logitpart + row);
            float4 o;
            o.x = 1.f / (1.f + expf(-(red[0] + lp.x + bo)));
            o.y = 1.f / (1.f + expf(-(red[1] + lp.y + bo)));
            o.z = 1.f / (1.f + expf(-(red[2] + lp.z + bo)));
            o.w = 1.f / (1.f + expf(-(red[3] + lp.w + bo)));
            *(float4*)(att + row) = o;
        }
    }
}

// ---------------------------------------------------------------------------
extern "C" void kernel_launch(void* const* d_in, const int* in_sizes, int n_in,
                              void* d_out, int out_size, void* d_ws, size_t ws_size,
                              hipStream_t stream)
{
    const float* feats  = (const float*)d_in[0];
    const int*   nbr    = (const int*)d_in[1];
    const float* W_init = (const float*)d_in[2];
    const float* b_init = (const float*)d_in[3];
    const float* g_init = (const float*)d_in[4];
    const float* be_init= (const float*)d_in[5];
    const float* m_init = (const float*)d_in[6];
    const float* v_init = (const float*)d_in[7];
    const float* W_br   = (const float*)d_in[8];
    const float* b_br   = (const float*)d_in[9];
    const float* g_br   = (const float*)d_in[10];
    const float* be_br  = (const float*)d_in[11];
    const float* m_br   = (const float*)d_in[12];
    const float* v_br   = (const float*)d_in[13];
    const float* W_out  = (const float*)d_in[14];
    const float* b_out  = (const float*)d_in[15];
    float* att = (float*)d_out;

    char* ws = (char*)d_ws;
    size_t off = 0;
    auto take = [&](size_t bytes) -> char* {
        char* p = ws + off;
        off = (off + bytes + 255) & ~(size_t)255;
        return p;
    };
    __bf16* fpad      = (__bf16*)take((size_t)(NV + 1) * 64 * 2);
    __bf16* xpad      = (__bf16*)take((size_t)(NV + 1) * 64 * 2);
    __bf16* wpk       = (__bf16*)take((size_t)4 * 27 * 4096 * 2);
    float*  scale     = (float*)take(4 * 64 * 4);
    float*  shiftb    = (float*)take(4 * 64 * 4);
    float*  logitpart = (float*)take((size_t)NV * 4);
    (void)in_sizes; (void)n_in; (void)out_size; (void)ws_size;

    prep_feats_k<<<25001, 256, 0, stream>>>(feats, fpad, xpad);
    prep_w_k<<<1728, 256, 0, stream>>>(W_init, W_br, wpk);
    prep_bn_k<<<1, 256, 0, stream>>>(b_init, g_init, be_init, m_init, v_init,
                                     b_br, g_br, be_br, m_br, v_br, scale, shiftb);
    conv_init_k<<<GRID_CONV, 256, 0, stream>>>(fpad, nbr, wpk, scale, shiftb,
                                               W_out, xpad, logitpart);
    conv_br_k<<<GRID_CONV, 256, 0, stream>>>(xpad, nbr, wpk, scale, shiftb,
                                             W_out, b_out, logitpart, att);
}

// Round 6
// 462.935 us; speedup vs baseline: 2.0780x; 1.2861x over previous
//
#include <hip/hip_runtime.h>
#include <hip/hip_bf16.h>
#include <math.h>

#define NV 400000
#define ROWS_BLK 128
#define GRID_CONV 3125   // NV / 128 exactly

typedef __bf16 bfv8 __attribute__((ext_vector_type(8)));
typedef float f32x4 __attribute__((ext_vector_type(4)));

// async global->LDS staging, 16B per lane
#define GLOAD_LDS16(gp, lp) __builtin_amdgcn_global_load_lds(                 \
    (const __attribute__((address_space(1))) void*)(gp),                     \
    (__attribute__((address_space(3))) void*)(lp), 16, 0, 0)

// ---------------------------------------------------------------------------
// prep: feats (f32) -> fpad (bf16, N+1 rows, row N = 0); zero xpad row N too
// ---------------------------------------------------------------------------
__global__ void prep_feats_k(const float* __restrict__ feats,
                             __bf16* __restrict__ fpad,
                             __bf16* __restrict__ xpad)
{
    long t = (long)blockIdx.x * blockDim.x + threadIdx.x;
    long base = t * 4;
    const long nfeat = (long)NV * 64;
    const long total = (long)(NV + 1) * 64;
    if (base < total) {
        float x0 = 0.f, x1 = 0.f, x2 = 0.f, x3 = 0.f;
        if (base < nfeat) {
            const float4 v = *(const float4*)(feats + base);
            x0 = v.x; x1 = v.y; x2 = v.z; x3 = v.w;
        }
        union { __bf16 b[4]; ushort4 u; } pk;
        pk.b[0] = (__bf16)x0; pk.b[1] = (__bf16)x1;
        pk.b[2] = (__bf16)x2; pk.b[3] = (__bf16)x3;
        *(ushort4*)(fpad + base) = pk.u;
    }
    if (t < 64) xpad[(long)NV * 64 + t] = (__bf16)0.f;
}

// ---------------------------------------------------------------------------
// prep: pack weights into MFMA B-fragment layout.
// wpk[s][k][kc][cb][lane][i] = W_s[k][cin][cout], cin = kc*32+(lane>>4)*8+i,
// cout = cb*16+(lane&15).  s=0: W_init, s=1..3: W_br[d].
// ---------------------------------------------------------------------------
__global__ void prep_w_k(const float* __restrict__ Winit,
                         const float* __restrict__ Wbr,
                         __bf16* __restrict__ wpk)
{
    int e = blockIdx.x * 256 + threadIdx.x;
    int i  = e & 7;
    int l  = (e >> 3) & 63;
    int cb = (e >> 9) & 3;
    int kc = (e >> 11) & 1;
    int kk = e >> 12;          // s*27 + k
    int k  = kk % 27;
    int s  = kk / 27;
    int cin  = kc * 32 + (l >> 4) * 8 + i;
    int cout = cb * 16 + (l & 15);
    float v = (s == 0) ? Winit[(k * 64 + cin) * 64 + cout]
                       : Wbr[(((s - 1) * 27 + k) * 64 + cin) * 64 + cout];
    wpk[e] = (__bf16)v;
}

// ---------------------------------------------------------------------------
// prep: fold BN (+ conv bias) into scale/shift:  y = conv*sc + sh
// ---------------------------------------------------------------------------
__global__ void prep_bn_k(const float* __restrict__ b_init, const float* __restrict__ g_init,
                          const float* __restrict__ be_init, const float* __restrict__ m_init,
                          const float* __restrict__ v_init,
                          const float* __restrict__ b_br, const float* __restrict__ g_br,
                          const float* __restrict__ be_br, const float* __restrict__ m_br,
                          const float* __restrict__ v_br,
                          float* __restrict__ scale, float* __restrict__ shiftb)
{
    int t = threadIdx.x;          // 0..255
    int s = t >> 6, c = t & 63;
    float g, be, m, v, b;
    if (s == 0) { g = g_init[c]; be = be_init[c]; m = m_init[c]; v = v_init[c]; b = b_init[c]; }
    else { int o = (s - 1) * 64 + c; g = g_br[o]; be = be_br[o]; m = m_br[o]; v = v_br[o]; b = b_br[o]; }
    float sc = g / sqrtf(v + 1e-5f);
    scale[t]  = sc;
    shiftb[t] = (b - m) * sc + be;
}

// ---------------------------------------------------------------------------
// tap helpers — 32 rows per wave (2 row-groups of 16)
// ---------------------------------------------------------------------------
struct Idx2 { int v[2]; };

__device__ __forceinline__ Idx2 load_idx(const int* __restrict__ nbr_t,
                                         long base, int l15)
{
    Idx2 r;
#pragma unroll
    for (int rg = 0; rg < 2; rg++) {
        long rr = base + rg * 16 + l15;
        r.v[rg] = nbr_t[rr];
    }
    return r;
}

// stage one tap's packed B (8 KB = 4096 bf16) into LDS; 8 chunks, 4 waves x 2
__device__ __forceinline__ void stage_b(const __bf16* __restrict__ wtap,
                                        __bf16* lds_dst, int wid, int lane)
{
#pragma unroll
    for (int j = 0; j < 2; j++) {
        int chunk = wid * 2 + j;
        const __bf16* gp = wtap + chunk * 512 + lane * 8;  // per-lane global src
        __bf16* lp = lds_dst + chunk * 512;                // wave-uniform LDS base
        GLOAD_LDS16(gp, lp);
    }
}

// issue A gathers for one tap into registers (normal loads; compiler tracks)
__device__ __forceinline__ void issue_A(const __bf16* __restrict__ src,
                                        const Idx2 idx, int lg,
                                        bfv8 a0[2], bfv8 a1[2])
{
#pragma unroll
    for (int rg = 0; rg < 2; rg++) {
        const bfv8* ar = (const bfv8*)(src + (size_t)idx.v[rg] * 64);
        a0[rg] = ar[lg];       // k = 0..31
        a1[rg] = ar[4 + lg];   // k = 32..63
    }
}

// 16 MFMAs for one tap; B frags JIT from LDS
__device__ __forceinline__ void mfma_tap(const __bf16* bbuf, int lane,
                                         const bfv8 a0[2], const bfv8 a1[2],
                                         f32x4 acc[2][4])
{
    const bfv8* wp = (const bfv8*)bbuf;
#pragma unroll
    for (int cb = 0; cb < 4; cb++) {
        bfv8 b0 = wp[cb * 64 + lane];
#pragma unroll
        for (int rg = 0; rg < 2; rg++)
            acc[rg][cb] = __builtin_amdgcn_mfma_f32_16x16x32_bf16(a0[rg], b0, acc[rg][cb], 0, 0, 0);
    }
#pragma unroll
    for (int cb = 0; cb < 4; cb++) {
        bfv8 b1 = wp[(4 + cb) * 64 + lane];
#pragma unroll
        for (int rg = 0; rg < 2; rg++)
            acc[rg][cb] = __builtin_amdgcn_mfma_f32_16x16x32_bf16(a1[rg], b1, acc[rg][cb], 0, 0, 0);
    }
}

// ---------------------------------------------------------------------------
// Pipeline (stage distance 2, A-prefetch 1, idx-prefetch 2, 4 LDS buffers):
//   iter k: issue_A(k+1) | stage(k+2) | load_idx(k+3) | vmcnt(8) | barrier |
//           mfma(k)
// Safety: mfma(k)'s buffer staged at k-2, retired by wait(k-1), published by
//   barrier(k-1).  stage(k) overwrites bbuf[(k+2)&3], last read by mfma(k-2),
//   which every wave finished BEFORE barrier(k-1) -> no read/write race.
// ---------------------------------------------------------------------------

// ---------------------------------------------------------------------------
// conv_init: x_init = bnrelu(conv(fpad, nbr[0..26], W_init)) -> xpad (bf16)
//            + logitpart[row] = x_init[row] . W_out
// smem: 4 x 4096 bf16 B-buffers; epilogue tile aliases buffers 0..1 (guarded
// by a full __syncthreads after the last tap).
// ---------------------------------------------------------------------------
__global__ __launch_bounds__(256, 4)
void conv_init_k(const __bf16* __restrict__ fpad, const int* __restrict__ nbr,
                 const __bf16* __restrict__ wpk, const float* __restrict__ scale,
                 const float* __restrict__ shiftb, const float* __restrict__ wout,
                 __bf16* __restrict__ xpad, float* __restrict__ logitpart)
{
    __shared__ __bf16 smem[4 * 4096];
    __bf16* tile = smem;
    const int tid = threadIdx.x;
    const int wid = tid >> 6, lane = tid & 63;
    const int l15 = lane & 15, lg = lane >> 4;
    const long base = (long)blockIdx.x * ROWS_BLK + wid * 32;

    f32x4 acc[2][4];
    f32x4 z = {0.f, 0.f, 0.f, 0.f};
#pragma unroll
    for (int a = 0; a < 2; a++)
#pragma unroll
        for (int b = 0; b < 4; b++) acc[a][b] = z;

    // prologue: stage taps 0..1, load idx 0..2, drain
    stage_b(wpk,                    smem + 0 * 4096, wid, lane);
    stage_b(wpk + (size_t)1 * 4096, smem + 1 * 4096, wid, lane);
    Idx2 i0 = load_idx(nbr,                  base, l15);
    Idx2 i1 = load_idx(nbr + (size_t)1 * NV, base, l15);
    Idx2 i2 = load_idx(nbr + (size_t)2 * NV, base, l15);
    __syncthreads();

    bfv8 aC0[2], aC1[2], aN0[2], aN1[2];
    issue_A(fpad, i0, lg, aC0, aC1);

#pragma unroll 2
    for (int k = 0; k < 25; k++) {
        issue_A(fpad, i1, lg, aN0, aN1);                                       // 4 vmem
        stage_b(wpk + (size_t)(k + 2) * 4096, smem + ((k + 2) & 3) * 4096, wid, lane); // 2
        int tn = (k + 3 < 27) ? (k + 3) : 26;
        Idx2 inew = load_idx(nbr + (size_t)tn * NV, base, l15);                // 2
        asm volatile("s_waitcnt vmcnt(8)" ::: "memory");
        __builtin_amdgcn_s_barrier();
        mfma_tap(smem + (k & 3) * 4096, lane, aC0, aC1, acc);
#pragma unroll
        for (int rg = 0; rg < 2; rg++) { aC0[rg] = aN0[rg]; aC1[rg] = aN1[rg]; }
        i1 = i2; i2 = inew;
    }
    // drain-based tail: taps 25,26
    for (int k = 25; k < 27; k++) {
        if (k < 26) issue_A(fpad, i1, lg, aN0, aN1);
        __syncthreads();
        mfma_tap(smem + (k & 3) * 4096, lane, aC0, aC1, acc);
#pragma unroll
        for (int rg = 0; rg < 2; rg++) { aC0[rg] = aN0[rg]; aC1[rg] = aN1[rg]; }
        i1 = i2;
    }

    float sc[4], sh[4], wo[4];
#pragma unroll
    for (int cb = 0; cb < 4; cb++) {
        int col = cb * 16 + l15;
        sc[cb] = scale[col]; sh[cb] = shiftb[col]; wo[cb] = wout[col];
    }
    float lacc[2][4];
#pragma unroll
    for (int rg = 0; rg < 2; rg++)
#pragma unroll
        for (int j = 0; j < 4; j++) lacc[rg][j] = 0.f;

    __syncthreads();   // all taps done before tile overwrites B-buffers 0..1
#pragma unroll
    for (int rg = 0; rg < 2; rg++)
#pragma unroll
        for (int cb = 0; cb < 4; cb++)
#pragma unroll
            for (int j = 0; j < 4; j++) {
                float y = fmaxf(acc[rg][cb][j] * sc[cb] + sh[cb], 0.f);
                lacc[rg][j] += y * wo[cb];
                tile[(wid * 32 + rg * 16 + lg * 4 + j) * 64 + cb * 16 + l15] = (__bf16)y;
            }
    __syncthreads();

    // coalesced write: 2 threads per row, 64B each
    {
        int r = tid >> 1, h = tid & 1;
        long grow = (long)blockIdx.x * ROWS_BLK + r;
        const f32x4* srcp = (const f32x4*)(tile + r * 64 + h * 32);
        f32x4* dst = (f32x4*)(xpad + grow * 64 + h * 32);
#pragma unroll
        for (int q = 0; q < 4; q++) dst[q] = srcp[q];
    }

#pragma unroll
    for (int rg = 0; rg < 2; rg++) {
        float red[4];
#pragma unroll
        for (int j = 0; j < 4; j++) {
            float t = lacc[rg][j];
            t += __shfl_xor(t, 1, 64);
            t += __shfl_xor(t, 2, 64);
            t += __shfl_xor(t, 4, 64);
            t += __shfl_xor(t, 8, 64);
            red[j] = t;
        }
        if (l15 == 0) {
            long row = base + rg * 16 + lg * 4;
            float4 o; o.x = red[0]; o.y = red[1]; o.z = red[2]; o.w = red[3];
            *(float4*)(logitpart + row) = o;
        }
    }
}

// ---------------------------------------------------------------------------
// conv_br: 3 branches flattened into one 81-tap pipelined stream.
// logit = sum_d (bnrelu_d . W_out) + logitpart + b_out;  att = sigmoid(logit)
// ---------------------------------------------------------------------------
__global__ __launch_bounds__(256, 4)
void conv_br_k(const __bf16* __restrict__ xpad, const int* __restrict__ nbr,
               const __bf16* __restrict__ wpk, const float* __restrict__ scale,
               const float* __restrict__ shiftb, const float* __restrict__ wout,
               const float* __restrict__ bout, const float* __restrict__ logitpart,
               float* __restrict__ att)
{
    __shared__ __bf16 bbuf[4][4096];
    const int tid = threadIdx.x;
    const int wid = tid >> 6, lane = tid & 63;
    const int l15 = lane & 15, lg = lane >> 4;
    const long base = (long)blockIdx.x * ROWS_BLK + wid * 32;

    float wo[4];
#pragma unroll
    for (int cb = 0; cb < 4; cb++) wo[cb] = wout[cb * 16 + l15];

    float lacc[2][4];
#pragma unroll
    for (int rg = 0; rg < 2; rg++)
#pragma unroll
        for (int j = 0; j < 4; j++) lacc[rg][j] = 0.f;

    f32x4 acc[2][4];
    f32x4 z = {0.f, 0.f, 0.f, 0.f};
#pragma unroll
    for (int a = 0; a < 2; a++)
#pragma unroll
        for (int b = 0; b < 4; b++) acc[a][b] = z;

    // per-branch epilogue: fold BN+ReLU into logit accumulator, reset acc
    auto do_epi = [&](int d) {
        float sc[4], sh[4];
#pragma unroll
        for (int cb = 0; cb < 4; cb++) {
            int col = (d + 1) * 64 + cb * 16 + l15;
            sc[cb] = scale[col]; sh[cb] = shiftb[col];
        }
#pragma unroll
        for (int rg = 0; rg < 2; rg++)
#pragma unroll
            for (int cb = 0; cb < 4; cb++)
#pragma unroll
                for (int j = 0; j < 4; j++) {
                    float y = fmaxf(acc[rg][cb][j] * sc[cb] + sh[cb], 0.f);
                    lacc[rg][j] += y * wo[cb];
                }
#pragma unroll
        for (int a = 0; a < 2; a++)
#pragma unroll
            for (int b = 0; b < 4; b++) acc[a][b] = z;
    };

    // prologue: stage taps 0..1, load idx 0..2, drain
    stage_b(wpk + (size_t)27 * 4096, bbuf[0], wid, lane);
    stage_b(wpk + (size_t)28 * 4096, bbuf[1], wid, lane);
    Idx2 i0 = load_idx(nbr,                  base, l15);
    Idx2 i1 = load_idx(nbr + (size_t)1 * NV, base, l15);
    Idx2 i2 = load_idx(nbr + (size_t)2 * NV, base, l15);
    __syncthreads();

    bfv8 aC0[2], aC1[2], aN0[2], aN1[2];
    issue_A(xpad, i0, lg, aC0, aC1);

#pragma unroll 2
    for (int k = 0; k < 79; k++) {
        issue_A(xpad, i1, lg, aN0, aN1);                                         // 4 vmem
        stage_b(wpk + (size_t)(k + 2 + 27) * 4096, bbuf[(k + 2) & 3], wid, lane); // 2
        int tn = (k + 3 < 81) ? (k + 3) : 80;
        Idx2 inew = load_idx(nbr + (size_t)tn * NV, base, l15);                  // 2
        asm volatile("s_waitcnt vmcnt(8)" ::: "memory");
        __builtin_amdgcn_s_barrier();
        mfma_tap(bbuf[k & 3], lane, aC0, aC1, acc);
        if (k == 26 || k == 53) do_epi(k / 27);
#pragma unroll
        for (int rg = 0; rg < 2; rg++) { aC0[rg] = aN0[rg]; aC1[rg] = aN1[rg]; }
        i1 = i2; i2 = inew;
    }
    // drain-based tail: taps 79,80
    for (int k = 79; k < 81; k++) {
        if (k < 80) issue_A(xpad, i1, lg, aN0, aN1);
        __syncthreads();
        mfma_tap(bbuf[k & 3], lane, aC0, aC1, acc);
#pragma unroll
        for (int rg = 0; rg < 2; rg++) { aC0[rg] = aN0[rg]; aC1[rg] = aN1[rg]; }
        i1 = i2;
    }
    do_epi(2);

    float bo = bout[0];
#pragma unroll
    for (int rg = 0; rg < 2; rg++) {
        float red[4];
#pragma unroll
        for (int j = 0; j < 4; j++) {
            float t = lacc[rg][j];
            t += __shfl_xor(t, 1, 64);
            t += __shfl_xor(t, 2, 64);
            t += __shfl_xor(t, 4, 64);
            t += __shfl_xor(t, 8, 64);
            red[j] = t;
        }
        if (l15 == 0) {
            long row = base + rg * 16 + lg * 4;
            float4 lp = *(const float4*)(logitpart + row);
            float4 o;
            o.x = 1.f / (1.f + expf(-(red[0] + lp.x + bo)));
            o.y = 1.f / (1.f + expf(-(red[1] + lp.y + bo)));
            o.z = 1.f / (1.f + expf(-(red[2] + lp.z + bo)));
            o.w = 1.f / (1.f + expf(-(red[3] + lp.w + bo)));
            *(float4*)(att + row) = o;
        }
    }
}

// ---------------------------------------------------------------------------
extern "C" void kernel_launch(void* const* d_in, const int* in_sizes, int n_in,
                              void* d_out, int out_size, void* d_ws, size_t ws_size,
                              hipStream_t stream)
{
    const float* feats  = (const float*)d_in[0];
    const int*   nbr    = (const int*)d_in[1];
    const float* W_init = (const float*)d_in[2];
    const float* b_init = (const float*)d_in[3];
    const float* g_init = (const float*)d_in[4];
    const float* be_init= (const float*)d_in[5];
    const float* m_init = (const float*)d_in[6];
    const float* v_init = (const float*)d_in[7];
    const float* W_br   = (const float*)d_in[8];
    const float* b_br   = (const float*)d_in[9];
    const float* g_br   = (const float*)d_in[10];
    const float* be_br  = (const float*)d_in[11];
    const float* m_br   = (const float*)d_in[12];
    const float* v_br   = (const float*)d_in[13];
    const float* W_out  = (const float*)d_in[14];
    const float* b_out  = (const float*)d_in[15];
    float* att = (float*)d_out;

    char* ws = (char*)d_ws;
    size_t off = 0;
    auto take = [&](size_t bytes) -> char* {
        char* p = ws + off;
        off = (off + bytes + 255) & ~(size_t)255;
        return p;
    };
    __bf16* fpad      = (__bf16*)take((size_t)(NV + 1) * 64 * 2);
    __bf16* xpad      = (__bf16*)take((size_t)(NV + 1) * 64 * 2);
    __bf16* wpk       = (__bf16*)take((size_t)4 * 27 * 4096 * 2);
    float*  scale     = (float*)take(4 * 64 * 4);
    float*  shiftb    = (float*)take(4 * 64 * 4);
    float*  logitpart = (float*)take((size_t)NV * 4);
    (void)in_sizes; (void)n_in; (void)out_size; (void)ws_size;

    prep_feats_k<<<25001, 256, 0, stream>>>(feats, fpad, xpad);
    prep_w_k<<<1728, 256, 0, stream>>>(W_init, W_br, wpk);
    prep_bn_k<<<1, 256, 0, stream>>>(b_init, g_init, be_init, m_init, v_init,
                                     b_br, g_br, be_br, m_br, v_br, scale, shiftb);
    conv_init_k<<<GRID_CONV, 256, 0, stream>>>(fpad, nbr, wpk, scale, shiftb,
                                               W_out, xpad, logitpart);
    conv_br_k<<<GRID_CONV, 256, 0, stream>>>(xpad, nbr, wpk, scale, shiftb,
                                             W_out, b_out, logitpart, att);
}